// Round 4
// baseline (1448.712 us; speedup 1.0000x reference)
//
#include <hip/hip_runtime.h>
#include <hip/hip_bf16.h>

// RPNHead fused kernel for MI355X (gfx950).
// Strategy: bf16 MFMA (16x16x32) direct conv-as-GEMM.
//   main GEMM: M = 128 positions (8x16 spatial tile), N = 512 shared channels,
//              K = 2304 (9 taps x 256 in-ch), per-block.
//   A: halo tile (10x18xCchunk) staged fp32->bf16 in LDS, XOR-swizzled, dbuf.
//   B: w_share pre-transposed to bf16 [co][k] in workspace (L2-resident).
//   Epilogue: s -> LDS bf16 (swizzled), head GEMM K=512 -> 18 ch, softmax via
//             shfl_xor pair trick, scatter writes to the 3 concatenated outputs.
//
// R3 changes vs R2:
//  - __launch_bounds__(512, 2): dynamic LDS hid the 1-block/CU limit from the
//    compiler; its 4-wave/SIMD heuristic capped VGPRs at 128 and SPILLED the
//    accumulators to scratch (VGPR_Count=128, WRITE_SIZE=2GB vs 17MB demand).
//    2 waves/SIMD -> 256 VGPR budget, fits ~230 live regs, no spills.
//  - non-temporal halo loads (via ext_vector f32x4 — the builtin rejects
//    HIP_vector_type): input has zero cross-block reuse; keep it from
//    evicting the 2.36MB weight matrix out of the 4MiB/XCD L2.

typedef __attribute__((ext_vector_type(8))) short short8;
typedef __attribute__((ext_vector_type(4))) float f32x4;

#define HALO_B 23040          // 10*18*64 bf16 bytes per chunk buffer
#define LDS_BYTES 131072      // s buffer 128*512*2 (>= 2*HALO_B)

static __device__ __forceinline__ unsigned short f2bf(float f) {
    unsigned u = __float_as_uint(f);
    u += 0x7fffu + ((u >> 16) & 1u);   // round-to-nearest-even
    return (unsigned short)(u >> 16);
}

// ---- prep: transpose w_share [2304][512] f32 -> wt [512][2304] bf16 ----
__global__ void prep_wt(const float* __restrict__ w, unsigned short* __restrict__ wt) {
    int t = blockIdx.x * 256 + threadIdx.x;       // 288 k-groups * 512 co = 147456
    if (t >= 147456) return;
    int co = t & 511;
    int k0 = (t >> 9) << 3;
    short8 v;
#pragma unroll
    for (int j = 0; j < 8; ++j)
        v[j] = (short)f2bf(w[(size_t)(k0 + j) * 512 + co]);
    *(short8*)(wt + (size_t)co * 2304 + k0) = v;
}

// ---- prep: head weights -> wh [32][512] bf16 (rows 0..5 cls, 6..17 box, rest 0)
__global__ void prep_whead(const float* __restrict__ wc, const float* __restrict__ wb,
                           unsigned short* __restrict__ wh) {
    int t = blockIdx.x * 256 + threadIdx.x;       // 32*512 = 16384
    if (t >= 16384) return;
    int j = t >> 9, k = t & 511;
    float v = 0.f;
    if (j < 6) v = wc[k * 6 + j];
    else if (j < 18) v = wb[k * 12 + (j - 6)];
    wh[t] = f2bf(v);
}

__global__ __launch_bounds__(512, 2) void rpn_main(
    const float* __restrict__ p2, const float* __restrict__ p3,
    const float* __restrict__ p4, const float* __restrict__ p5,
    const float* __restrict__ p6,
    const unsigned short* __restrict__ wt, const unsigned short* __restrict__ wh,
    const float* __restrict__ bsh, const float* __restrict__ bcl,
    const float* __restrict__ bbx, float* __restrict__ out) {
    extern __shared__ char smem[];
    const int tid = threadIdx.x;
    const int lane = tid & 63, wid = tid >> 6;

    // ---- block -> (level, batch, tile) ----
    int b = blockIdx.x, lvl, rem;
    if (b < 1024)      { lvl = 0; rem = b; }
    else if (b < 1280) { lvl = 1; rem = b - 1024; }
    else if (b < 1344) { lvl = 2; rem = b - 1280; }
    else if (b < 1360) { lvl = 3; rem = b - 1344; }
    else               { lvl = 4; rem = b - 1360; }
    const int Hs[5]   = {256, 128, 64, 32, 16};
    const int LOFF[5] = {0, 196608, 245760, 258048, 261120};
    const int H = Hs[lvl];
    const int lvloff = LOFF[lvl];
    const float* inp = lvl == 0 ? p2 : lvl == 1 ? p3 : lvl == 2 ? p4 : lvl == 3 ? p5 : p6;
    const int tilesX = H >> 4;                 // W/16
    const int tilesPerImg = (H >> 3) * tilesX; // (H/8)*(W/16)
    const int n = rem / tilesPerImg;
    const int tt = rem % tilesPerImg;
    const int y0 = (tt / tilesX) << 3;
    const int x0 = (tt % tilesX) << 4;
    const float* inb = inp + (size_t)n * H * H * 256;

    // ---- accumulators: wave owns 128 pos x 64 ch -> 8 M-frags x 4 N-frags ----
    f32x4 acc[8][4];
    const f32x4 zero4 = {0.f, 0.f, 0.f, 0.f};
#pragma unroll
    for (int i = 0; i < 8; ++i)
#pragma unroll
        for (int j = 0; j < 4; ++j) acc[i][j] = zero4;

    // ---- staging regs: up to 3 units of 8 channels each ----
    float sv[3][8];
    int saddr[3];

    auto stage_load = [&](int cc) {
#pragma unroll
        for (int i = 0; i < 3; ++i) {
            int u = tid + (i << 9);
            saddr[i] = -1;
            if (u < 1440) {                       // 10*18*8 units
                int ch8 = u & 7;
                int rc = u >> 3;
                int col = rc % 18;
                int row = rc / 18;
                int y = y0 + row - 1, x = x0 + col - 1;
                saddr[i] = rc * 128 + ((ch8 * 16) ^ ((col & 7) << 4));
                if (y >= 0 && y < H && x >= 0 && x < H) {
                    const f32x4* src =
                        (const f32x4*)(inb + (size_t)(y * H + x) * 256 + cc * 64 + ch8 * 8);
                    f32x4 a = __builtin_nontemporal_load(src);
                    f32x4 c = __builtin_nontemporal_load(src + 1);
                    sv[i][0] = a[0]; sv[i][1] = a[1]; sv[i][2] = a[2]; sv[i][3] = a[3];
                    sv[i][4] = c[0]; sv[i][5] = c[1]; sv[i][6] = c[2]; sv[i][7] = c[3];
                } else {
#pragma unroll
                    for (int j = 0; j < 8; ++j) sv[i][j] = 0.f;
                }
            }
        }
    };
    auto stage_write = [&](char* buf) {
#pragma unroll
        for (int i = 0; i < 3; ++i) {
            if (saddr[i] >= 0) {
                short8 v;
#pragma unroll
                for (int j = 0; j < 8; ++j) v[j] = (short)f2bf(sv[i][j]);
                *(short8*)(buf + saddr[i]) = v;
            }
        }
    };

    stage_load(0);
    stage_write(smem);
    __syncthreads();

    // ---- main K loop: 4 channel-chunks x 9 taps x 2 k-steps ----
    for (int cc = 0; cc < 4; ++cc) {
        if (cc < 3) stage_load(cc + 1);
        const char* hb = smem + (cc & 1) * HALO_B;
#pragma unroll
        for (int ty = 0; ty < 3; ++ty) {
#pragma unroll
            for (int tx = 0; tx < 3; ++tx) {
#pragma unroll
                for (int kk = 0; kk < 2; ++kk) {
                    const int hc = (lane & 15) + tx;
                    const int chb = (kk * 32 + ((lane >> 4) << 3)) * 2;
                    const int sw = (hc & 7) << 4;
                    short8 af[8];
#pragma unroll
                    for (int mi = 0; mi < 8; ++mi) {
                        int hr = mi + ty;
                        af[mi] = *(const short8*)(hb + (hr * 18 + hc) * 128 + (chb ^ sw));
                    }
                    const int kof = (ty * 3 + tx) * 256 + cc * 64 + kk * 32 + ((lane >> 4) << 3);
                    short8 bf[4];
#pragma unroll
                    for (int ni = 0; ni < 4; ++ni) {
                        int co = wid * 64 + ni * 16 + (lane & 15);
                        bf[ni] = *(const short8*)(wt + (size_t)co * 2304 + kof);
                    }
#pragma unroll
                    for (int mi = 0; mi < 8; ++mi)
#pragma unroll
                        for (int ni = 0; ni < 4; ++ni)
                            acc[mi][ni] = __builtin_amdgcn_mfma_f32_16x16x32_bf16(
                                af[mi], bf[ni], acc[mi][ni], 0, 0, 0);
                }
            }
        }
        if (cc < 3) stage_write(smem + ((cc + 1) & 1) * HALO_B);
        __syncthreads();
    }

    // ---- s = relu(acc + b_share) -> LDS bf16 [128][512], swizzled ----
#pragma unroll
    for (int ni = 0; ni < 4; ++ni) {
        int co = wid * 64 + ni * 16 + (lane & 15);
        float bias = bsh[co];
#pragma unroll
        for (int mi = 0; mi < 8; ++mi) {
#pragma unroll
            for (int r = 0; r < 4; ++r) {
                int p = mi * 16 + ((lane >> 4) << 2) + r;
                float v = fmaxf(acc[mi][ni][r] + bias, 0.f);
                int addr = (p * 1024 + co * 2) ^ ((p & 7) << 4);
                *(unsigned short*)(smem + addr) = f2bf(v);
            }
        }
    }
    __syncthreads();

    // ---- head GEMM: wave wid handles its 16 positions (spatial row wid) ----
    f32x4 h0 = zero4, h1 = zero4;
    {
        const int prow = (wid << 4) + (lane & 15);
        const int swz = (prow & 7) << 4;
        const int kbase = (lane >> 4) << 3;
#pragma unroll
        for (int kk = 0; kk < 16; ++kk) {
            int k = (kk << 5) + kbase;
            short8 a = *(const short8*)(smem + ((prow * 1024 + k * 2) ^ swz));
            short8 b0 = *(const short8*)(wh + (lane & 15) * 512 + k);
            short8 b1 = *(const short8*)(wh + (16 + (lane & 15)) * 512 + k);
            h0 = __builtin_amdgcn_mfma_f32_16x16x32_bf16(a, b0, h0, 0, 0, 0);
            h1 = __builtin_amdgcn_mfma_f32_16x16x32_bf16(a, b1, h1, 0, 0, 0);
        }
    }

    // ---- epilogue: bias, softmax(pairs), scatter to concatenated outputs ----
    const int jj = lane & 15;
    float bh0;
    if (jj < 6) bh0 = bcl[jj]; else bh0 = bbx[jj - 6];
    float bh1 = 0.f;
    if (jj < 2) bh1 = bbx[10 + jj];
    const size_t O1 = 1047552, O2 = 2095104;
    const int yg = y0 + wid;
    const size_t nb = (size_t)n * 261888;
#pragma unroll
    for (int r = 0; r < 4; ++r) {
        int c_sp = ((lane >> 4) << 2) + r;
        int xg = x0 + c_sp;
        size_t base3 = (size_t)lvloff + (size_t)(yg * H + xg) * 3;
        float v0 = h0[r] + bh0;
        float po = __shfl_xor(v0, 1, 64);       // partner class logit
        if (jj < 6) {
            int a_ = jj >> 1, c_ = jj & 1;
            size_t idx = (nb + base3 + a_) * 2 + c_;
            out[idx] = v0;                                      // class_logit
            out[O1 + idx] = 1.f / (1.f + expf(po - v0));        // class_prob
        } else {
            int q = jj - 6;
            out[O2 + (nb + base3 + (q >> 2)) * 4 + (q & 3)] = v0;   // box 0..9
        }
        if (jj < 2) {
            float v1 = h1[r] + bh1;             // j = 16+jj -> box ch 10,11
            out[O2 + (nb + base3 + 2) * 4 + (2 + jj)] = v1;
        }
    }
}

extern "C" void kernel_launch(void* const* d_in, const int* in_sizes, int n_in,
                              void* d_out, int out_size, void* d_ws, size_t ws_size,
                              hipStream_t stream) {
    const float* p2  = (const float*)d_in[0];
    const float* p3  = (const float*)d_in[1];
    const float* p4  = (const float*)d_in[2];
    const float* p5  = (const float*)d_in[3];
    const float* p6  = (const float*)d_in[4];
    const float* wsh = (const float*)d_in[5];
    const float* bsh = (const float*)d_in[6];
    const float* wcl = (const float*)d_in[7];
    const float* bcl = (const float*)d_in[8];
    const float* wbx = (const float*)d_in[9];
    const float* bbx = (const float*)d_in[10];
    unsigned short* wt = (unsigned short*)d_ws;           // 512*2304 bf16
    unsigned short* wh = wt + 512 * 2304;                 // 32*512 bf16
    float* out = (float*)d_out;

    (void)hipFuncSetAttribute((const void*)rpn_main,
                              hipFuncAttributeMaxDynamicSharedMemorySize, LDS_BYTES);
    prep_wt<<<576, 256, 0, stream>>>(wsh, wt);
    prep_whead<<<64, 256, 0, stream>>>(wcl, wbx, wh);
    rpn_main<<<1364, 512, LDS_BYTES, stream>>>(p2, p3, p4, p5, p6, wt, wh,
                                               bsh, bcl, bbx, out);
}

// Round 6
// 1292.557 us; speedup vs baseline: 1.1208x; 1.1208x over previous
//
#include <hip/hip_runtime.h>
#include <hip/hip_bf16.h>

// RPNHead fused kernel for MI355X (gfx950).
// Strategy: bf16 MFMA (16x16x32) direct conv-as-GEMM.
//   main GEMM: M = 128 positions (8x16 spatial tile), N = 512 shared channels,
//              K = 2304 (9 taps x 256 in-ch), per-block.
//   A: inputs pre-converted to bf16 (prep_bf16); halo tile staged via
//      global_load_lds DMA (linear LDS dest + inverse-swizzled global source,
//      so the read-side XOR swizzle still sees conflict-free banks). OOB halo
//      slots are zero-filled once at start and never DMA-written.
//   B: w_share pre-transposed to bf16 [co][k] in workspace (L2-resident).
//   Epilogue: s -> LDS bf16 (swizzled), head GEMM K=512 -> 18 ch, softmax via
//             shfl_xor pair trick, scatter writes to the 3 concatenated outputs.
//
// R6 changes vs R4 (spill elimination — R4 post-mortem):
//   R4's VGPR_Count stayed 128 with __launch_bounds__(512,2): the 2nd arg
//   empirically acted as min-BLOCKS/CU (2 blocks -> 4 waves/SIMD -> 128-VGPR
//   cap), so acc kept spilling to scratch (2GB writes). Now:
//   - __launch_bounds__(512, 1): >=256-VGPR budget under either semantics
//     (128KiB LDS caps at 1 block/CU regardless).
//   - staging VGPRs removed from the hot kernel: fp32->bf16 pre-pass kernel +
//     register-free global_load_lds DMA halo staging. Live ~200 < 256.

typedef __attribute__((ext_vector_type(8))) short short8;
typedef __attribute__((ext_vector_type(4))) float f32x4;

#define HALO_B 23040          // 10*18*64ch bf16 bytes per chunk buffer
#define LDS_BYTES 131072      // s buffer 128*512*2 (>= 2*HALO_B staging)

static __device__ __forceinline__ unsigned short f2bf(float f) {
    unsigned u = __float_as_uint(f);
    u += 0x7fffu + ((u >> 16) & 1u);   // round-to-nearest-even
    return (unsigned short)(u >> 16);
}

static __device__ __forceinline__ void gload_lds16(const void* g, void* l) {
    __builtin_amdgcn_global_load_lds(
        (const __attribute__((address_space(1))) unsigned int*)g,
        (__attribute__((address_space(3))) unsigned int*)l, 16, 0, 0);
}

// ---- prep: transpose w_share [2304][512] f32 -> wt [512][2304] bf16 ----
__global__ void prep_wt(const float* __restrict__ w, unsigned short* __restrict__ wt) {
    int t = blockIdx.x * 256 + threadIdx.x;       // 288 k-groups * 512 co = 147456
    if (t >= 147456) return;
    int co = t & 511;
    int k0 = (t >> 9) << 3;
    short8 v;
#pragma unroll
    for (int j = 0; j < 8; ++j)
        v[j] = (short)f2bf(w[(size_t)(k0 + j) * 512 + co]);
    *(short8*)(wt + (size_t)co * 2304 + k0) = v;
}

// ---- prep: head weights -> wh [32][512] bf16 (rows 0..5 cls, 6..17 box, rest 0)
__global__ void prep_whead(const float* __restrict__ wc, const float* __restrict__ wb,
                           unsigned short* __restrict__ wh) {
    int t = blockIdx.x * 256 + threadIdx.x;       // 32*512 = 16384
    if (t >= 16384) return;
    int j = t >> 9, k = t & 511;
    float v = 0.f;
    if (j < 6) v = wc[k * 6 + j];
    else if (j < 18) v = wb[k * 12 + (j - 6)];
    wh[t] = f2bf(v);
}

// ---- prep: all 5 pyramid inputs fp32 -> bf16, concatenated in ws ----
__global__ void prep_bf16(const float* __restrict__ p2, const float* __restrict__ p3,
                          const float* __restrict__ p4, const float* __restrict__ p5,
                          const float* __restrict__ p6, unsigned short* __restrict__ xb) {
    const size_t NU = 5586944;                    // 44,695,552 elems / 8
    for (size_t u = (size_t)blockIdx.x * blockDim.x + threadIdx.x; u < NU;
         u += (size_t)gridDim.x * blockDim.x) {
        size_t e = u << 3;
        const float* src;
        if (e < 33554432u)      src = p2 + e;
        else if (e < 41943040u) src = p3 + (e - 33554432u);
        else if (e < 44040192u) src = p4 + (e - 41943040u);
        else if (e < 44564480u) src = p5 + (e - 44040192u);
        else                    src = p6 + (e - 44564480u);
        f32x4 a = __builtin_nontemporal_load((const f32x4*)src);
        f32x4 b = __builtin_nontemporal_load((const f32x4*)src + 1);
        short8 v;
        v[0] = (short)f2bf(a[0]); v[1] = (short)f2bf(a[1]);
        v[2] = (short)f2bf(a[2]); v[3] = (short)f2bf(a[3]);
        v[4] = (short)f2bf(b[0]); v[5] = (short)f2bf(b[1]);
        v[6] = (short)f2bf(b[2]); v[7] = (short)f2bf(b[3]);
        *(short8*)(xb + e) = v;
    }
}

__global__ __launch_bounds__(512, 1) void rpn_main(
    const unsigned short* __restrict__ xb,
    const unsigned short* __restrict__ wt, const unsigned short* __restrict__ wh,
    const float* __restrict__ bsh, const float* __restrict__ bcl,
    const float* __restrict__ bbx, float* __restrict__ out) {
    extern __shared__ char smem[];
    const int tid = threadIdx.x;
    const int lane = tid & 63, wid = tid >> 6;

    // ---- block -> (level, batch, tile) ----
    int b = blockIdx.x, lvl, rem;
    if (b < 1024)      { lvl = 0; rem = b; }
    else if (b < 1280) { lvl = 1; rem = b - 1024; }
    else if (b < 1344) { lvl = 2; rem = b - 1280; }
    else if (b < 1360) { lvl = 3; rem = b - 1344; }
    else               { lvl = 4; rem = b - 1360; }
    const int Hs[5]   = {256, 128, 64, 32, 16};
    const int LOFF[5] = {0, 196608, 245760, 258048, 261120};          // anchor rows
    const size_t XOFF[5] = {0, 33554432u, 41943040u, 44040192u, 44564480u}; // bf16 elems
    const int H = Hs[lvl];
    const int lvloff = LOFF[lvl];
    const int tilesX = H >> 4;                 // W/16
    const int tilesPerImg = (H >> 3) * tilesX; // (H/8)*(W/16)
    const int n = rem / tilesPerImg;
    const int tt = rem % tilesPerImg;
    const int y0 = (tt / tilesX) << 3;
    const int x0 = (tt % tilesX) << 4;
    const unsigned short* inb = xb + XOFF[lvl] + (size_t)n * H * H * 256;

    // ---- zero both staging buffers (OOB halo slots stay zero forever) ----
    {
        const int4 z4 = {0, 0, 0, 0};
#pragma unroll
        for (int i = 0; i < 6; ++i) {
            int s = tid + (i << 9);
            if (s < 2880) *(int4*)(smem + s * 16) = z4;   // 2*HALO_B / 16
        }
    }
    __syncthreads();

    // ---- accumulators: wave owns 128 pos x 64 ch -> 8 M-frags x 4 N-frags ----
    f32x4 acc[8][4];
    const f32x4 zero4 = {0.f, 0.f, 0.f, 0.f};
#pragma unroll
    for (int i = 0; i < 8; ++i)
#pragma unroll
        for (int j = 0; j < 4; ++j) acc[i][j] = zero4;

    // ---- register-free halo staging: global_load_lds DMA ----
    // LDS linear: unit u = rc*8 + slot, 16B each. Slot s holds channel-group
    // s ^ (col&7)  (inverse swizzle applied to the per-lane GLOBAL address),
    // so the read side's  addr = base ^ ((col&7)<<4)  finds channel-group ch.
    auto stage = [&](int cc, int bufsel) {
        char* sbase = smem + bufsel * HALO_B;
#pragma unroll
        for (int r = 0; r < 3; ++r) {
            int u = (r << 9) + tid;               // 1440 units of 16B
            int rc = u >> 3, s8 = u & 7;
            int col = rc % 18, row = rc / 18;
            int y = y0 + row - 1, x = x0 + col - 1;
            if (u < 1440 && y >= 0 && y < H && x >= 0 && x < H) {
                int ch = s8 ^ (col & 7);
                const unsigned short* src =
                    inb + (size_t)(y * H + x) * 256 + cc * 64 + ch * 8;
                // wave-uniform LDS base; HW adds lane*16
                char* ldst = sbase + (((r << 9) + (wid << 6)) << 4);
                gload_lds16(src, ldst);
            }
        }
    };

    stage(0, 0);
    __syncthreads();

    // ---- main K loop: 4 channel-chunks x 9 taps x 2 k-steps ----
    for (int cc = 0; cc < 4; ++cc) {
        if (cc < 3) stage(cc + 1, (cc + 1) & 1);
        const char* hb = smem + (cc & 1) * HALO_B;
#pragma unroll
        for (int ty = 0; ty < 3; ++ty) {
#pragma unroll
            for (int tx = 0; tx < 3; ++tx) {
#pragma unroll
                for (int kk = 0; kk < 2; ++kk) {
                    const int hc = (lane & 15) + tx;
                    const int chb = (kk * 32 + ((lane >> 4) << 3)) * 2;
                    const int sw = (hc & 7) << 4;
                    short8 af[8];
#pragma unroll
                    for (int mi = 0; mi < 8; ++mi) {
                        int hr = mi + ty;
                        af[mi] = *(const short8*)(hb + (hr * 18 + hc) * 128 + (chb ^ sw));
                    }
                    const int kof = (ty * 3 + tx) * 256 + cc * 64 + kk * 32 + ((lane >> 4) << 3);
                    short8 bf[4];
#pragma unroll
                    for (int ni = 0; ni < 4; ++ni) {
                        int co = wid * 64 + ni * 16 + (lane & 15);
                        bf[ni] = *(const short8*)(wt + (size_t)co * 2304 + kof);
                    }
#pragma unroll
                    for (int mi = 0; mi < 8; ++mi)
#pragma unroll
                        for (int ni = 0; ni < 4; ++ni)
                            acc[mi][ni] = __builtin_amdgcn_mfma_f32_16x16x32_bf16(
                                af[mi], bf[ni], acc[mi][ni], 0, 0, 0);
                }
            }
        }
        __syncthreads();
    }

    // ---- s = relu(acc + b_share) -> LDS bf16 [128][512], swizzled ----
#pragma unroll
    for (int ni = 0; ni < 4; ++ni) {
        int co = wid * 64 + ni * 16 + (lane & 15);
        float bias = bsh[co];
#pragma unroll
        for (int mi = 0; mi < 8; ++mi) {
#pragma unroll
            for (int r = 0; r < 4; ++r) {
                int p = mi * 16 + ((lane >> 4) << 2) + r;
                float v = fmaxf(acc[mi][ni][r] + bias, 0.f);
                int addr = (p * 1024 + co * 2) ^ ((p & 7) << 4);
                *(unsigned short*)(smem + addr) = f2bf(v);
            }
        }
    }
    __syncthreads();

    // ---- head GEMM: wave wid handles its 16 positions (spatial row wid) ----
    f32x4 h0 = zero4, h1 = zero4;
    {
        const int prow = (wid << 4) + (lane & 15);
        const int swz = (prow & 7) << 4;
        const int kbase = (lane >> 4) << 3;
#pragma unroll
        for (int kk = 0; kk < 16; ++kk) {
            int k = (kk << 5) + kbase;
            short8 a = *(const short8*)(smem + ((prow * 1024 + k * 2) ^ swz));
            short8 b0 = *(const short8*)(wh + (lane & 15) * 512 + k);
            short8 b1 = *(const short8*)(wh + (16 + (lane & 15)) * 512 + k);
            h0 = __builtin_amdgcn_mfma_f32_16x16x32_bf16(a, b0, h0, 0, 0, 0);
            h1 = __builtin_amdgcn_mfma_f32_16x16x32_bf16(a, b1, h1, 0, 0, 0);
        }
    }

    // ---- epilogue: bias, softmax(pairs), scatter to concatenated outputs ----
    const int jj = lane & 15;
    float bh0;
    if (jj < 6) bh0 = bcl[jj]; else bh0 = bbx[jj - 6];
    float bh1 = 0.f;
    if (jj < 2) bh1 = bbx[10 + jj];
    const size_t O1 = 1047552, O2 = 2095104;
    const int yg = y0 + wid;
    const size_t nb = (size_t)n * 261888;
#pragma unroll
    for (int r = 0; r < 4; ++r) {
        int c_sp = ((lane >> 4) << 2) + r;
        int xg = x0 + c_sp;
        size_t base3 = (size_t)lvloff + (size_t)(yg * H + xg) * 3;
        float v0 = h0[r] + bh0;
        float po = __shfl_xor(v0, 1, 64);       // partner class logit
        if (jj < 6) {
            int a_ = jj >> 1, c_ = jj & 1;
            size_t idx = (nb + base3 + a_) * 2 + c_;
            out[idx] = v0;                                      // class_logit
            out[O1 + idx] = 1.f / (1.f + expf(po - v0));        // class_prob
        } else {
            int q = jj - 6;
            out[O2 + (nb + base3 + (q >> 2)) * 4 + (q & 3)] = v0;   // box 0..9
        }
        if (jj < 2) {
            float v1 = h1[r] + bh1;             // j = 16+jj -> box ch 10,11
            out[O2 + (nb + base3 + 2) * 4 + (2 + jj)] = v1;
        }
    }
}

extern "C" void kernel_launch(void* const* d_in, const int* in_sizes, int n_in,
                              void* d_out, int out_size, void* d_ws, size_t ws_size,
                              hipStream_t stream) {
    const float* p2  = (const float*)d_in[0];
    const float* p3  = (const float*)d_in[1];
    const float* p4  = (const float*)d_in[2];
    const float* p5  = (const float*)d_in[3];
    const float* p6  = (const float*)d_in[4];
    const float* wsh = (const float*)d_in[5];
    const float* bsh = (const float*)d_in[6];
    const float* wcl = (const float*)d_in[7];
    const float* bcl = (const float*)d_in[8];
    const float* wbx = (const float*)d_in[9];
    const float* bbx = (const float*)d_in[10];
    unsigned short* wt = (unsigned short*)d_ws;           // 512*2304 bf16
    unsigned short* wh = wt + 1179648;                    // 32*512 bf16
    unsigned short* xb = wh + 16384;                      // 44,695,552 bf16 inputs
    float* out = (float*)d_out;

    (void)hipFuncSetAttribute((const void*)rpn_main,
                              hipFuncAttributeMaxDynamicSharedMemorySize, LDS_BYTES);
    prep_wt<<<576, 256, 0, stream>>>(wsh, wt);
    prep_whead<<<64, 256, 0, stream>>>(wcl, wbx, wh);
    prep_bf16<<<4096, 256, 0, stream>>>(p2, p3, p4, p5, p6, xb);
    rpn_main<<<1364, 512, LDS_BYTES, stream>>>(xb, wt, wh, bsh, bcl, bbx, out);
}